// Round 2
// baseline (352.043 us; speedup 1.0000x reference)
//
#include <hip/hip_runtime.h>
#include <hip/hip_bf16.h>

typedef _Float16 f16x8 __attribute__((ext_vector_type(8)));
typedef _Float16 f16x4 __attribute__((ext_vector_type(4)));
typedef float f32x4 __attribute__((ext_vector_type(4)));
typedef int i32x4 __attribute__((ext_vector_type(4)));

__device__ __forceinline__ float bf2f(unsigned short u) {
  union { unsigned int i; float f; } x; x.i = ((unsigned int)u) << 16; return x.f;
}
// clamp-to-finite fp16 convert: any upstream bug shows finite, not NaN
__device__ __forceinline__ _Float16 h16(float f) {
  return (_Float16)fminf(fmaxf(f, -60000.f), 60000.f);
}

// accurate -log(u): series for u near 1 (1-u exact by Sterbenz there)
__device__ __forceinline__ float neglog(float u) {
  if (u > 0.99f) {
    const float d = 1.0f - u;
    return d + 0.5f * d * d + (1.0f / 3.0f) * d * d * d;
  }
  return -__logf(u);
}

// plain butterfly sum across 64 lanes
__device__ __forceinline__ float wsum(float v) {
#pragma unroll
  for (int off = 1; off < 64; off <<= 1) v += __shfl_xor(v, off, 64);
  return v;
}

// St row-keyed XOR swizzle: byte ^= ((row&7)<<4)  (element bits 3-5).
// Stride-1024 rows -> Phase-C b128 column reads land on banks
// ((lq ^ (lm&7)) << 2): balanced 8 lanes per 4-bank group = conflict-free.
// Phase-B accesses are row-uniform (constant XOR per instr) = unchanged.
__device__ __forceinline__ int sidx(int row, int col) {
  return ((row) * 1024 + (col)) ^ (((row) & 7) << 3);
}

// ---------------------------------------------------------------------------
// Kernel 0: input dtype detector (gumbel_u in (1e-6,1-1e-6)).
// flag: 0 = bf16 inputs, 1 = fp32 inputs.
// ---------------------------------------------------------------------------
__global__ void detect_dtype(const unsigned short* __restrict__ g, int* __restrict__ flag) {
  const int lane = threadIdx.x;
  const float f = bf2f(g[lane * 2]);
  const bool ok = (f >= 8e-7f) && (f <= 1.0f);
  const unsigned long long m = __ballot(ok);
  if (lane == 0) *flag = (m == ~0ull) ? 0 : 1;
}

// ---------------------------------------------------------------------------
// Kernel 0b: convert hidden + Wq/Wk/Wv to fp16 once.
// dst: [hid 2M | Wq 1M | Wk 1M | Wv 1M] halves.
// ---------------------------------------------------------------------------
__global__ __launch_bounds__(256) void cvt_inputs(
    const void* __restrict__ h, const void* __restrict__ wq,
    const void* __restrict__ wk, const void* __restrict__ wv,
    const int* __restrict__ flag, _Float16* __restrict__ dst)
{
  const int y = blockIdx.y;
  const int n = (y == 0) ? (2 * 1024 * 1024) : (1024 * 1024);
  const int idx = (blockIdx.x * 256 + threadIdx.x) * 4;
  if (idx >= n) return;
  const void* src = (y == 0) ? h : (y == 1) ? wq : (y == 2) ? wk : wv;
  const size_t base = (y == 0) ? 0 : (size_t)(2 * 1024 * 1024) + (size_t)(y - 1) * 1024 * 1024;
  f16x4 o;
  if (*flag) {
    f32x4 v = *(const f32x4*)((const float*)src + idx);
#pragma unroll
    for (int j = 0; j < 4; j++) o[j] = h16(v[j]);
  } else {
    union { unsigned long long q; unsigned short u[4]; } ld;
    ld.q = *(const unsigned long long*)((const unsigned short*)src + idx);
#pragma unroll
    for (int j = 0; j < 4; j++) o[j] = h16(bf2f(ld.u[j]));
  }
  *(f16x4*)(dst + base + idx) = o;
}

// ---------------------------------------------------------------------------
// Kernel 0c: convert dist_emb [2047][64] to fp16 once (runs after qkv_gemm,
// into the dead Wq slot of the cvt buffer).
// ---------------------------------------------------------------------------
__global__ __launch_bounds__(256) void cvt_emb(
    const void* __restrict__ de, const int* __restrict__ flag,
    _Float16* __restrict__ e16)
{
  const int idx = (blockIdx.x * 256 + threadIdx.x) * 4;
  if (idx >= 2047 * 64) return;
  f16x4 o;
  if (*flag) {
    f32x4 v = *(const f32x4*)((const float*)de + idx);
#pragma unroll
    for (int j = 0; j < 4; j++) o[j] = h16(v[j]);
  } else {
    union { unsigned long long q; unsigned short u[4]; } ld;
    ld.q = *(const unsigned long long*)((const unsigned short*)de + idx);
#pragma unroll
    for (int j = 0; j < 4; j++) o[j] = h16(bf2f(ld.u[j]));
  }
  *(f16x4*)(e16 + idx) = o;
}

// ---------------------------------------------------------------------------
// Kernel 1: QKV projection on pre-converted fp16. NT gemm 2048 x 3072 x 1024.
// 64x128 tiles, BK=64 -> 768 blocks (3/CU) for latency hiding.
// ---------------------------------------------------------------------------
__global__ __launch_bounds__(256) void qkv_gemm(
    const _Float16* __restrict__ cvt,   // [hid | Wq | Wk | Wv]
    const unsigned short* __restrict__ bq, const unsigned short* __restrict__ bk,
    const unsigned short* __restrict__ bv,
    const int* __restrict__ flag,
    _Float16* __restrict__ q_ws, _Float16* __restrict__ k_ws,
    _Float16* __restrict__ v_ws)
{
  __shared__ _Float16 At[64][72];   // 64 x 64 fp16, +8 pad
  __shared__ _Float16 Bt[128][72];  // 128 x 64 fp16, +8 pad
  const int flg = *flag;
  const int tn = blockIdx.x;        // 32 M-tiles of 64 rows
  const int to = blockIdx.y;        // 24 N-tiles of 128 cols over [q|k|v]
  const int mat = to >> 3;          // 0=q 1=k 2=v
  const int o0 = (to & 7) * 128;
  const _Float16* hid16 = cvt;
  const _Float16* W16 = cvt + (size_t)(2 * 1024 * 1024) + (size_t)mat * 1024 * 1024;
  const unsigned short* bias = (mat == 0) ? bq : (mat == 1) ? bk : bv;
  const float* biasf = (const float*)bias;
  const int tid = threadIdx.x;
  const int lane = tid & 63, wave = tid >> 6;
  const int wm = (wave >> 1) * 32, wn = (wave & 1) * 64;  // 2x2 quadrants 32x64
  const int lm = lane & 15, lq = lane >> 4;
  f32x4 acc[2][4] = {};

  for (int kc = 0; kc < 1024; kc += 64) {
    __syncthreads();
#pragma unroll
    for (int i = 0; i < 2; i++) {  // A: 64 rows x 8 chunks of 16B
      const int cid = i * 256 + tid;
      const int r = cid >> 3, c8 = cid & 7;
      *(i32x4*)(&At[r][c8 * 8]) =
          *(const i32x4*)(hid16 + (size_t)(tn * 64 + r) * 1024 + kc + c8 * 8);
    }
#pragma unroll
    for (int i = 0; i < 4; i++) {  // B: 128 rows x 8 chunks of 16B
      const int cid = i * 256 + tid;
      const int r = cid >> 3, c8 = cid & 7;
      *(i32x4*)(&Bt[r][c8 * 8]) =
          *(const i32x4*)(W16 + (size_t)(o0 + r) * 1024 + kc + c8 * 8);
    }
    __syncthreads();
    f16x8 af[2][2], bfr[4][2];
#pragma unroll
    for (int mt = 0; mt < 2; mt++)
#pragma unroll
      for (int k2 = 0; k2 < 2; k2++)
        af[mt][k2] = *(const f16x8*)(&At[wm + mt * 16 + lm][k2 * 32 + lq * 8]);
#pragma unroll
    for (int nt = 0; nt < 4; nt++)
#pragma unroll
      for (int k2 = 0; k2 < 2; k2++)
        bfr[nt][k2] = *(const f16x8*)(&Bt[wn + nt * 16 + lm][k2 * 32 + lq * 8]);
#pragma unroll
    for (int mt = 0; mt < 2; mt++)
#pragma unroll
      for (int nt = 0; nt < 4; nt++)
#pragma unroll
        for (int k2 = 0; k2 < 2; k2++)
          acc[mt][nt] = __builtin_amdgcn_mfma_f32_16x16x32_f16(
              af[mt][k2], bfr[nt][k2], acc[mt][nt], 0, 0, 0);
  }

  // epilogue: C/D layout col=lane&15, row=quad*4+reg
  _Float16* dst = (mat == 0) ? q_ws : (mat == 1) ? k_ws : v_ws;
#pragma unroll
  for (int nt = 0; nt < 4; nt++) {
    const int ol = o0 + wn + nt * 16 + lm;
    const float bias_v = flg ? biasf[ol] : bf2f(bias[ol]);
    const int hh = ol >> 6, dd = ol & 63;
#pragma unroll
    for (int mt = 0; mt < 2; mt++) {
#pragma unroll
      for (int rg = 0; rg < 4; rg++) {
        const int n = tn * 64 + wm + mt * 16 + lq * 4 + rg;  // b*1024+s
        const int b = n >> 10, s = n & 1023;
        dst[((size_t)(b * 16 + hh) * 1024 + s) * 64 + dd] = h16(acc[mt][nt][rg] + bias_v);
      }
    }
  }
}

// ---------------------------------------------------------------------------
// Kernel 1b: transpose v [bh][s][64] -> vT [bh][64][s] via LDS 64x64 tiles.
// ---------------------------------------------------------------------------
__global__ __launch_bounds__(256) void transpose_v(
    const _Float16* __restrict__ v_ws, _Float16* __restrict__ vT_ws)
{
  __shared__ unsigned short Tt[64 * 66];
  const int st = blockIdx.x;   // 16 s-tiles
  const int bh = blockIdx.y;   // 32
  const int tid = threadIdx.x;
  const unsigned short* src = (const unsigned short*)(v_ws + (size_t)bh * 65536);
#pragma unroll
  for (int i = 0; i < 2; i++) {
    const int cid = i * 256 + tid;
    const int r = cid >> 3, c8 = cid & 7;   // row in tile, 8-half chunk
    union { i32x4 v; unsigned int w[4]; } ld;
    ld.v = *(const i32x4*)(src + (size_t)(st * 64 + r) * 64 + c8 * 8);
#pragma unroll
    for (int w = 0; w < 4; w++)
      *(unsigned int*)(&Tt[r * 66 + c8 * 8 + w * 2]) = ld.w[w];
  }
  __syncthreads();
  const int d = tid >> 2, sc = (tid & 3) * 16;
  unsigned short us[16];
#pragma unroll
  for (int j = 0; j < 16; j++) us[j] = Tt[(sc + j) * 66 + d];
  unsigned short* dst = (unsigned short*)(vT_ws + (size_t)bh * 65536 + (size_t)d * 1024 + st * 64 + sc);
#pragma unroll
  for (int w = 0; w < 4; w++)
    *(unsigned long long*)(dst + w * 4) = *(unsigned long long*)(us + w * 4);
}

// ---------------------------------------------------------------------------
// Kernel 2: fused scores + rel-pos + gumbel double-softmax + PV.
// One block (4 waves) per (b, h, 16-row l-tile). 2048 blocks.
//
// vs previous version:
//  - St is exactly 32 KB (stride 1024 + row-XOR swizzle) -> 5 blocks/CU
//    instead of 4 (was the occupancy cap), conflict-free Phase-C reads.
//  - gumbel rows 0,1 loads issued BEFORE Phase A: ~900cy HBM latency hides
//    under the whole score computation instead of stalling Phase B.
//  - Phase C: rolling 1-deep V prefetch; first pair issued before the
//    B->C barrier (uses registers freed by dead gumbel buffers).
// ---------------------------------------------------------------------------
__global__ __launch_bounds__(256, 5) void attn_kernel(
    const _Float16* __restrict__ q_ws, const _Float16* __restrict__ k_ws,
    const _Float16* __restrict__ vT_ws,
    const _Float16* __restrict__ e16,      // [2047][64] fp16
    const unsigned short* __restrict__ gumbel_u,
    const unsigned short* __restrict__ mask,
    const int* __restrict__ flag,
    float* __restrict__ out)
{
  __shared__ _Float16 St[16 * 1024];  // scores -> probs in place, 32768 B
  const int flg = *flag;
  const int blk = blockIdx.x;
  const int lt = blk & 63;
  const int bh = blk >> 6;
  const int b = bh >> 4, h = bh & 15;
  const int L = lt * 16;
  const _Float16* qp = q_ws + (size_t)bh * 65536;
  const _Float16* kp = k_ws + (size_t)bh * 65536;
  const _Float16* vp = vT_ws + (size_t)bh * 65536;
  const unsigned short* up = gumbel_u + (size_t)bh * 1024 * 1024;
  const float* upf = (const float*)gumbel_u + (size_t)bh * 1024 * 1024;
  const float* maskf = (const float*)mask;
  const int tid = threadIdx.x, wave = tid >> 6, lane = tid & 63;
  const int lm = lane & 15, lq = lane >> 4;
  const int rr = wave * 16 + lm;         // this wave's score column within chunk

  // Q tile A-fragments held for the whole block
  const f16x8 qa0 = *(const f16x8*)(qp + (L + lm) * 64 + lq * 8);
  const f16x8 qa1 = *(const f16x8*)(qp + (L + lm) * 64 + 32 + lq * 8);

  // ---- gumbel load machinery (Phase B), defined early so rows 0,1 can be
  // issued before Phase A: these loads depend on nothing and their ~900cy
  // HBM latency hides under the whole score computation.
  const int i0 = wave * 4;
  f32x4 uA[4], uB[4];
  auto ldrow = [&](f32x4 (&dst)[4], int i) {
    if (flg) {
      const float* urf = upf + (size_t)(L + i) * 1024 + lane * 4;
#pragma unroll
      for (int c = 0; c < 4; c++) dst[c] = *(const f32x4*)(urf + c * 256);
    } else {
      const unsigned short* ur = up + (size_t)(L + i) * 1024 + lane * 4;
#pragma unroll
      for (int c = 0; c < 4; c++) {
        union { unsigned long long q; unsigned short u[4]; } ld;
        ld.q = *(const unsigned long long*)(ur + c * 256);
        f32x4 v;
#pragma unroll
        for (int j = 0; j < 4; j++) v[j] = bf2f(ld.u[j]);
        dst[c] = v;
      }
    }
  };
  ldrow(uA, i0);
  ldrow(uB, i0 + 1);

  // ---- Phase A (no barriers): St = (Q.K^T + Q.E[l-r+1023])/8 + mask ----
  // Wave-private rel-pos via ds_bpermute (see R0 notes).
#pragma unroll 2
  for (int R = 0; R < 1024; R += 64) {
    const _Float16* krow = kp + (R + rr) * 64;
    const f16x8 kb0 = *(const f16x8*)(krow + lq * 8);
    const f16x8 kb1 = *(const f16x8*)(krow + 32 + lq * 8);
    const int base = L - R + 1008 - wave * 16;   // in [0, 2016]
    const int r0e = base + lm;                   // <= 2031, >= 0
    int r1e = base + 16 + lm;                    // <= 2047: clamp
    if (r1e > 2046) r1e = 2046;                  // o=31 never consumed
    const f16x8 e00 = *(const f16x8*)(e16 + (size_t)r0e * 64 + lq * 8);
    const f16x8 e01 = *(const f16x8*)(e16 + (size_t)r0e * 64 + 32 + lq * 8);
    const f16x8 e10 = *(const f16x8*)(e16 + (size_t)r1e * 64 + lq * 8);
    const f16x8 e11 = *(const f16x8*)(e16 + (size_t)r1e * 64 + 32 + lq * 8);
    const float mval = flg ? maskf[b * 1024 + R + rr] : bf2f(mask[b * 1024 + R + rr]);

    f32x4 aqk = {0.f, 0.f, 0.f, 0.f};
    aqk = __builtin_amdgcn_mfma_f32_16x16x32_f16(qa0, kb0, aqk, 0, 0, 0);
    aqk = __builtin_amdgcn_mfma_f32_16x16x32_f16(qa1, kb1, aqk, 0, 0, 0);
    f32x4 au0 = {0.f, 0.f, 0.f, 0.f}, au1 = {0.f, 0.f, 0.f, 0.f};
    au0 = __builtin_amdgcn_mfma_f32_16x16x32_f16(qa0, e00, au0, 0, 0, 0);
    au0 = __builtin_amdgcn_mfma_f32_16x16x32_f16(qa1, e01, au0, 0, 0, 0);
    au1 = __builtin_amdgcn_mfma_f32_16x16x32_f16(qa0, e10, au1, 0, 0, 0);
    au1 = __builtin_amdgcn_mfma_f32_16x16x32_f16(qa1, e11, au1, 0, 0, 0);

#pragma unroll
    for (int rg = 0; rg < 4; rg++) {
      const int o = lq * 4 + rg + 15 - lm;             // [0,30]
      const int idx = ((lane & 48) | (o & 15)) << 2;   // byte index for bpermute
      const float u0 = __int_as_float(
          __builtin_amdgcn_ds_bpermute(idx, __float_as_int(au0[rg])));
      const float u1 = __int_as_float(
          __builtin_amdgcn_ds_bpermute(idx, __float_as_int(au1[rg])));
      const float uval = (o >= 16) ? u1 : u0;
      St[sidx(lq * 4 + rg, R + rr)] = h16((aqk[rg] + uval) * 0.125f + mval);
    }
  }

  // ---- Phase B: max-free double softmax ----
  auto dorow = [&](const f32x4 (&uv)[4], int i) {
    f16x4 sh[4];
#pragma unroll
    for (int c = 0; c < 4; c++)
      sh[c] = *(const f16x4*)(St + sidx(i, c * 256 + lane * 4));
    float num1[4][4];
    float s1 = 0.f;
#pragma unroll
    for (int c = 0; c < 4; c++)
#pragma unroll
      for (int j = 0; j < 4; j++) {
        const float s = (float)sh[c][j];
        const float nl = neglog(uv[c][j] + 1e-10f) + 1e-10f;
        num1[c][j] = __expf(s) * __builtin_amdgcn_rcpf(nl);
        s1 += num1[c][j];
      }
    s1 = wsum(s1);
    const float is1 = __builtin_amdgcn_rcpf(s1);
    float num2[4][4];
    float s2 = 0.f;
#pragma unroll
    for (int c = 0; c < 4; c++)
#pragma unroll
      for (int j = 0; j < 4; j++) {
        num2[c][j] = __expf((float)sh[c][j] + num1[c][j] * is1);  // TAU_1 = 1
        s2 += num2[c][j];
      }
    s2 = wsum(s2);
    const float is2 = __builtin_amdgcn_rcpf(s2);
#pragma unroll
    for (int c = 0; c < 4; c++) {
      f16x4 pw;
#pragma unroll
      for (int j = 0; j < 4; j++) pw[j] = (_Float16)(num2[c][j] * is2);
      *(f16x4*)(St + sidx(i, c * 256 + lane * 4)) = pw;
    }
  };

  __syncthreads();
  dorow(uA, i0);
  ldrow(uA, i0 + 2);
  dorow(uB, i0 + 1);
  ldrow(uB, i0 + 3);
  dorow(uA, i0 + 2);
  dorow(uB, i0 + 3);

  // pre-issue first V pair before the barrier (independent of LDS state);
  // latency overlaps with other waves arriving at the barrier.
  const _Float16* vrow = vp + (wave * 16 + lm) * 1024;  // V^T row d
  f16x8 vn0 = *(const f16x8*)(vrow + lq * 8);
  f16x8 vn1 = *(const f16x8*)(vrow + 32 + lq * 8);
  __syncthreads();

  // ---- Phase C: ctx[i][d] = sum_r P[i][r] * V[r][d]  (NT vs V^T) ----
  f32x4 co0 = {0.f, 0.f, 0.f, 0.f}, co1 = {0.f, 0.f, 0.f, 0.f};
#pragma unroll 4
  for (int r0 = 0; r0 < 1024; r0 += 64) {
    const f16x8 va0 = vn0, va1 = vn1;
    if (r0 < 960) {
      vn0 = *(const f16x8*)(vrow + r0 + 64 + lq * 8);
      vn1 = *(const f16x8*)(vrow + r0 + 96 + lq * 8);
    }
    const f16x8 pa0 = *(const f16x8*)(St + sidx(lm, r0 + lq * 8));
    const f16x8 pa1 = *(const f16x8*)(St + sidx(lm, r0 + 32 + lq * 8));
    co0 = __builtin_amdgcn_mfma_f32_16x16x32_f16(pa0, va0, co0, 0, 0, 0);
    co1 = __builtin_amdgcn_mfma_f32_16x16x32_f16(pa1, va1, co1, 0, 0, 0);
  }
  const f32x4 co = co0 + co1;
#pragma unroll
  for (int rg = 0; rg < 4; rg++) {
    const int i = lq * 4 + rg;
    out[(size_t)(b * 1024 + L + i) * 1024 + h * 64 + wave * 16 + lm] = co[rg];
  }
}

extern "C" void kernel_launch(void* const* d_in, const int* in_sizes, int n_in,
                              void* d_out, int out_size, void* d_ws, size_t ws_size,
                              hipStream_t stream) {
  const unsigned short* hidden = (const unsigned short*)d_in[0];
  const unsigned short* mask   = (const unsigned short*)d_in[1];
  const unsigned short* gum    = (const unsigned short*)d_in[2];
  const unsigned short* Wq     = (const unsigned short*)d_in[3];
  const unsigned short* bq     = (const unsigned short*)d_in[4];
  const unsigned short* Wk     = (const unsigned short*)d_in[5];
  const unsigned short* bk     = (const unsigned short*)d_in[6];
  const unsigned short* Wv     = (const unsigned short*)d_in[7];
  const unsigned short* bv     = (const unsigned short*)d_in[8];
  const unsigned short* de     = (const unsigned short*)d_in[9];

  int* flag = (int*)d_ws;                                        // 256 B
  _Float16* cvt16 = (_Float16*)((char*)d_ws + 256);              // 10 MB (dead after qkv)
  _Float16* q_ws  = cvt16 + (size_t)5 * 1024 * 1024;             // 4 MB
  _Float16* k_ws  = q_ws + (size_t)2 * 1024 * 1024;              // 4 MB
  _Float16* v_ws  = k_ws + (size_t)2 * 1024 * 1024;              // 4 MB
  _Float16* vT_ws = cvt16;             // reuse cvt16[0..2M) after qkv consumed it
  _Float16* e16   = cvt16 + (size_t)2 * 1024 * 1024;  // dead Wq slot, 256 KB
  float* out = (float*)d_out;

  detect_dtype<<<1, 64, 0, stream>>>(gum, flag);
  cvt_inputs<<<dim3(2048, 4), 256, 0, stream>>>(hidden, Wq, Wk, Wv, flag, cvt16);
  qkv_gemm<<<dim3(32, 24), 256, 0, stream>>>(cvt16, bq, bk, bv, flag,
                                             q_ws, k_ws, v_ws);
  cvt_emb<<<128, 256, 0, stream>>>(de, flag, e16);
  transpose_v<<<dim3(16, 32), 256, 0, stream>>>(v_ws, vT_ws);
  attn_kernel<<<2048, 256, 0, stream>>>(q_ws, k_ws, vT_ws, e16, gum, mask, flag, out);
}

// Round 4
// 344.427 us; speedup vs baseline: 1.0221x; 1.0221x over previous
//
#include <hip/hip_runtime.h>
#include <hip/hip_bf16.h>

typedef _Float16 f16x8 __attribute__((ext_vector_type(8)));
typedef _Float16 f16x4 __attribute__((ext_vector_type(4)));
typedef float f32x4 __attribute__((ext_vector_type(4)));
typedef int i32x4 __attribute__((ext_vector_type(4)));

__device__ __forceinline__ float bf2f(unsigned short u) {
  union { unsigned int i; float f; } x; x.i = ((unsigned int)u) << 16; return x.f;
}
// clamp-to-finite fp16 convert: any upstream bug shows finite, not NaN
__device__ __forceinline__ _Float16 h16(float f) {
  return (_Float16)fminf(fmaxf(f, -60000.f), 60000.f);
}

// accurate -log(u): series for u near 1 (1-u exact by Sterbenz there)
__device__ __forceinline__ float neglog(float u) {
  if (u > 0.99f) {
    const float d = 1.0f - u;
    return d + 0.5f * d * d + (1.0f / 3.0f) * d * d * d;
  }
  return -__logf(u);
}

// plain butterfly sum across 64 lanes
__device__ __forceinline__ float wsum(float v) {
#pragma unroll
  for (int off = 1; off < 64; off <<= 1) v += __shfl_xor(v, off, 64);
  return v;
}

// St row-keyed XOR swizzle: element idx ^ ((row&7)<<3) (byte bits 4-6).
// Stride-1024 rows -> Phase-C b128 column reads bank-balanced; Phase-B
// accesses are row-uniform (constant XOR per instr) = unchanged.
__device__ __forceinline__ int sidx(int row, int col) {
  return ((row) * 1024 + (col)) ^ (((row) & 7) << 3);
}

// Per-wave dtype detection: every wave reads the same first 64 bf16-shorts
// of gumbel (even indices) and ballots -> identical flag in all waves, no
// LDS, no barrier, no separate kernel. 0 = bf16 inputs, 1 = fp32 inputs.
__device__ __forceinline__ int wave_flag(const unsigned short* __restrict__ g, int tid) {
  const float f = bf2f(g[(tid & 63) * 2]);
  const unsigned long long m = __ballot((f >= 8e-7f) && (f <= 1.0f));
  return (m == ~0ull) ? 0 : 1;
}

// ---------------------------------------------------------------------------
// Kernel 0: convert hidden + Wq/Wk/Wv to fp16 once.
// dst: [hid 2M | Wq 1M | Wk 1M | Wv 1M] halves.
// ---------------------------------------------------------------------------
__global__ __launch_bounds__(256) void cvt_inputs(
    const void* __restrict__ h, const void* __restrict__ wq,
    const void* __restrict__ wk, const void* __restrict__ wv,
    const unsigned short* __restrict__ gum, _Float16* __restrict__ dst)
{
  const int flg = wave_flag(gum, threadIdx.x);
  const int y = blockIdx.y;
  const int n = (y == 0) ? (2 * 1024 * 1024) : (1024 * 1024);
  const int idx = (blockIdx.x * 256 + threadIdx.x) * 4;
  if (idx >= n) return;
  const void* src = (y == 0) ? h : (y == 1) ? wq : (y == 2) ? wk : wv;
  const size_t base = (y == 0) ? 0 : (size_t)(2 * 1024 * 1024) + (size_t)(y - 1) * 1024 * 1024;
  f16x4 o;
  if (flg) {
    f32x4 v = *(const f32x4*)((const float*)src + idx);
#pragma unroll
    for (int j = 0; j < 4; j++) o[j] = h16(v[j]);
  } else {
    union { unsigned long long q; unsigned short u[4]; } ld;
    ld.q = *(const unsigned long long*)((const unsigned short*)src + idx);
#pragma unroll
    for (int j = 0; j < 4; j++) o[j] = h16(bf2f(ld.u[j]));
  }
  *(f16x4*)(dst + base + idx) = o;
}

// ---------------------------------------------------------------------------
// Kernel 1: QKV projection on pre-converted fp16. NT gemm 2048 x 3072 x 1024.
// 64x128 tiles, BK=64 -> 768 blocks (3/CU) for latency hiding.
// ---------------------------------------------------------------------------
__global__ __launch_bounds__(256) void qkv_gemm(
    const _Float16* __restrict__ cvt,   // [hid | Wq | Wk | Wv]
    const unsigned short* __restrict__ bq, const unsigned short* __restrict__ bk,
    const unsigned short* __restrict__ bv,
    const unsigned short* __restrict__ gum,
    _Float16* __restrict__ q_ws, _Float16* __restrict__ k_ws,
    _Float16* __restrict__ v_ws)
{
  __shared__ _Float16 At[64][72];   // 64 x 64 fp16, +8 pad
  __shared__ _Float16 Bt[128][72];  // 128 x 64 fp16, +8 pad
  const int flg = wave_flag(gum, threadIdx.x);
  const int tn = blockIdx.x;        // 32 M-tiles of 64 rows
  const int to = blockIdx.y;        // 24 N-tiles of 128 cols over [q|k|v]
  const int mat = to >> 3;          // 0=q 1=k 2=v
  const int o0 = (to & 7) * 128;
  const _Float16* hid16 = cvt;
  const _Float16* W16 = cvt + (size_t)(2 * 1024 * 1024) + (size_t)mat * 1024 * 1024;
  const unsigned short* bias = (mat == 0) ? bq : (mat == 1) ? bk : bv;
  const float* biasf = (const float*)bias;
  const int tid = threadIdx.x;
  const int lane = tid & 63, wave = tid >> 6;
  const int wm = (wave >> 1) * 32, wn = (wave & 1) * 64;  // 2x2 quadrants 32x64
  const int lm = lane & 15, lq = lane >> 4;
  f32x4 acc[2][4] = {};

  for (int kc = 0; kc < 1024; kc += 64) {
    __syncthreads();
#pragma unroll
    for (int i = 0; i < 2; i++) {  // A: 64 rows x 8 chunks of 16B
      const int cid = i * 256 + tid;
      const int r = cid >> 3, c8 = cid & 7;
      *(i32x4*)(&At[r][c8 * 8]) =
          *(const i32x4*)(hid16 + (size_t)(tn * 64 + r) * 1024 + kc + c8 * 8);
    }
#pragma unroll
    for (int i = 0; i < 4; i++) {  // B: 128 rows x 8 chunks of 16B
      const int cid = i * 256 + tid;
      const int r = cid >> 3, c8 = cid & 7;
      *(i32x4*)(&Bt[r][c8 * 8]) =
          *(const i32x4*)(W16 + (size_t)(o0 + r) * 1024 + kc + c8 * 8);
    }
    __syncthreads();
    f16x8 af[2][2], bfr[4][2];
#pragma unroll
    for (int mt = 0; mt < 2; mt++)
#pragma unroll
      for (int k2 = 0; k2 < 2; k2++)
        af[mt][k2] = *(const f16x8*)(&At[wm + mt * 16 + lm][k2 * 32 + lq * 8]);
#pragma unroll
    for (int nt = 0; nt < 4; nt++)
#pragma unroll
      for (int k2 = 0; k2 < 2; k2++)
        bfr[nt][k2] = *(const f16x8*)(&Bt[wn + nt * 16 + lm][k2 * 32 + lq * 8]);
#pragma unroll
    for (int mt = 0; mt < 2; mt++)
#pragma unroll
      for (int nt = 0; nt < 4; nt++)
#pragma unroll
        for (int k2 = 0; k2 < 2; k2++)
          acc[mt][nt] = __builtin_amdgcn_mfma_f32_16x16x32_f16(
              af[mt][k2], bfr[nt][k2], acc[mt][nt], 0, 0, 0);
  }

  // epilogue: C/D layout col=lane&15, row=quad*4+reg
  _Float16* dst = (mat == 0) ? q_ws : (mat == 1) ? k_ws : v_ws;
#pragma unroll
  for (int nt = 0; nt < 4; nt++) {
    const int ol = o0 + wn + nt * 16 + lm;
    const float bias_v = flg ? biasf[ol] : bf2f(bias[ol]);
    const int hh = ol >> 6, dd = ol & 63;
#pragma unroll
    for (int mt = 0; mt < 2; mt++) {
#pragma unroll
      for (int rg = 0; rg < 4; rg++) {
        const int n = tn * 64 + wm + mt * 16 + lq * 4 + rg;  // b*1024+s
        const int b = n >> 10, s = n & 1023;
        dst[((size_t)(b * 16 + hh) * 1024 + s) * 64 + dd] = h16(acc[mt][nt][rg] + bias_v);
      }
    }
  }
}

// ---------------------------------------------------------------------------
// Kernel 2: transpose v [bh][s][64] -> vT [bh][64][s] via LDS 64x64 tiles,
// plus (grid y==32) dist_emb -> fp16 conversion. One launch instead of two.
// ---------------------------------------------------------------------------
__global__ __launch_bounds__(256) void transpose_v_emb(
    const _Float16* __restrict__ v_ws, _Float16* __restrict__ vT_ws,
    const void* __restrict__ de, const unsigned short* __restrict__ gum,
    _Float16* __restrict__ e16)
{
  __shared__ unsigned short Tt[64 * 66];
  const int tid = threadIdx.x;

  if (blockIdx.y == 32) {
    // dist_emb conversion: 2047*64 = 131008 halves = 32752 vec4 chunks
    const int flg = wave_flag(gum, tid);
    for (int c = blockIdx.x * 256 + tid; c < 32752; c += 16 * 256) {
      const int idx = c * 4;
      f16x4 o;
      if (flg) {
        f32x4 v = *(const f32x4*)((const float*)de + idx);
#pragma unroll
        for (int j = 0; j < 4; j++) o[j] = h16(v[j]);
      } else {
        union { unsigned long long q; unsigned short u[4]; } ld;
        ld.q = *(const unsigned long long*)((const unsigned short*)de + idx);
#pragma unroll
        for (int j = 0; j < 4; j++) o[j] = h16(bf2f(ld.u[j]));
      }
      *(f16x4*)(e16 + idx) = o;
    }
    return;
  }

  const int st = blockIdx.x;   // 16 s-tiles
  const int bh = blockIdx.y;   // 32
  const unsigned short* src = (const unsigned short*)(v_ws + (size_t)bh * 65536);
#pragma unroll
  for (int i = 0; i < 2; i++) {
    const int cid = i * 256 + tid;
    const int r = cid >> 3, c8 = cid & 7;   // row in tile, 8-half chunk
    union { i32x4 v; unsigned int w[4]; } ld;
    ld.v = *(const i32x4*)(src + (size_t)(st * 64 + r) * 64 + c8 * 8);
#pragma unroll
    for (int w = 0; w < 4; w++)
      *(unsigned int*)(&Tt[r * 66 + c8 * 8 + w * 2]) = ld.w[w];
  }
  __syncthreads();
  const int d = tid >> 2, sc = (tid & 3) * 16;
  unsigned short us[16];
#pragma unroll
  for (int j = 0; j < 16; j++) us[j] = Tt[(sc + j) * 66 + d];
  unsigned short* dst = (unsigned short*)(vT_ws + (size_t)bh * 65536 + (size_t)d * 1024 + st * 64 + sc);
#pragma unroll
  for (int w = 0; w < 4; w++)
    *(unsigned long long*)(dst + w * 4) = *(unsigned long long*)(us + w * 4);
}

// ---------------------------------------------------------------------------
// Kernel 3: fused scores + rel-pos + gumbel double-softmax + PV.
// One block (4 waves) per (b, h, 16-row l-tile). 2048 blocks.
//
// vs R2 (which regressed): gumbel loads are NOT hoisted above Phase A (that
// extended 32-reg live ranges across the whole loop -> scratch spills,
// +50 MB HBM). Instead: R1's placement (issue right after Phase A, before
// the barrier) deepened to 3 buffers, so each dorow has >=2 dorows of slack
// before its data is needed. launch_bounds(256,4): VGPR cap 128; expected
// alloc ~70-85, which still permits 5-block residency with the 32 KB St.
// ---------------------------------------------------------------------------
__global__ __launch_bounds__(256, 4) void attn_kernel(
    const _Float16* __restrict__ q_ws, const _Float16* __restrict__ k_ws,
    const _Float16* __restrict__ vT_ws,
    const _Float16* __restrict__ e16,      // [2047][64] fp16
    const unsigned short* __restrict__ gumbel_u,
    const unsigned short* __restrict__ mask,
    float* __restrict__ out)
{
  __shared__ _Float16 St[16 * 1024];  // scores -> probs in place, 32768 B
  const int tid = threadIdx.x, wave = tid >> 6, lane = tid & 63;
  const int flg = wave_flag(gumbel_u, tid);
  const int blk = blockIdx.x;
  const int lt = blk & 63;
  const int bh = blk >> 6;
  const int b = bh >> 4, h = bh & 15;
  const int L = lt * 16;
  const _Float16* qp = q_ws + (size_t)bh * 65536;
  const _Float16* kp = k_ws + (size_t)bh * 65536;
  const _Float16* vp = vT_ws + (size_t)bh * 65536;
  const unsigned short* up = gumbel_u + (size_t)bh * 1024 * 1024;
  const float* upf = (const float*)gumbel_u + (size_t)bh * 1024 * 1024;
  const float* maskf = (const float*)mask;
  const int lm = lane & 15, lq = lane >> 4;
  const int rr = wave * 16 + lm;         // this wave's score column within chunk

  // Q tile A-fragments held for the whole block
  const f16x8 qa0 = *(const f16x8*)(qp + (L + lm) * 64 + lq * 8);
  const f16x8 qa1 = *(const f16x8*)(qp + (L + lm) * 64 + 32 + lq * 8);

  // ---- Phase A (no barriers): St = (Q.K^T + Q.E[l-r+1023])/8 + mask ----
  // Wave-private rel-pos via ds_bpermute (see R0 notes).
#pragma unroll 2
  for (int R = 0; R < 1024; R += 64) {
    const _Float16* krow = kp + (R + rr) * 64;
    const f16x8 kb0 = *(const f16x8*)(krow + lq * 8);
    const f16x8 kb1 = *(const f16x8*)(krow + 32 + lq * 8);
    const int base = L - R + 1008 - wave * 16;   // in [0, 2016]
    const int r0e = base + lm;                   // <= 2031, >= 0
    int r1e = base + 16 + lm;                    // <= 2047: clamp
    if (r1e > 2046) r1e = 2046;                  // o=31 never consumed
    const f16x8 e00 = *(const f16x8*)(e16 + (size_t)r0e * 64 + lq * 8);
    const f16x8 e01 = *(const f16x8*)(e16 + (size_t)r0e * 64 + 32 + lq * 8);
    const f16x8 e10 = *(const f16x8*)(e16 + (size_t)r1e * 64 + lq * 8);
    const f16x8 e11 = *(const f16x8*)(e16 + (size_t)r1e * 64 + 32 + lq * 8);
    const float mval = flg ? maskf[b * 1024 + R + rr] : bf2f(mask[b * 1024 + R + rr]);

    f32x4 aqk = {0.f, 0.f, 0.f, 0.f};
    aqk = __builtin_amdgcn_mfma_f32_16x16x32_f16(qa0, kb0, aqk, 0, 0, 0);
    aqk = __builtin_amdgcn_mfma_f32_16x16x32_f16(qa1, kb1, aqk, 0, 0, 0);
    f32x4 au0 = {0.f, 0.f, 0.f, 0.f}, au1 = {0.f, 0.f, 0.f, 0.f};
    au0 = __builtin_amdgcn_mfma_f32_16x16x32_f16(qa0, e00, au0, 0, 0, 0);
    au0 = __builtin_amdgcn_mfma_f32_16x16x32_f16(qa1, e01, au0, 0, 0, 0);
    au1 = __builtin_amdgcn_mfma_f32_16x16x32_f16(qa0, e10, au1, 0, 0, 0);
    au1 = __builtin_amdgcn_mfma_f32_16x16x32_f16(qa1, e11, au1, 0, 0, 0);

#pragma unroll
    for (int rg = 0; rg < 4; rg++) {
      const int o = lq * 4 + rg + 15 - lm;             // [0,30]
      const int idx = ((lane & 48) | (o & 15)) << 2;   // byte index for bpermute
      const float u0 = __int_as_float(
          __builtin_amdgcn_ds_bpermute(idx, __float_as_int(au0[rg])));
      const float u1 = __int_as_float(
          __builtin_amdgcn_ds_bpermute(idx, __float_as_int(au1[rg])));
      const float uval = (o >= 16) ? u1 : u0;
      St[sidx(lq * 4 + rg, R + rr)] = h16((aqk[rg] + uval) * 0.125f + mval);
    }
  }

  // ---- Phase B: max-free double softmax, 3-deep gumbel prefetch ----
  const int i0 = wave * 4;
  f32x4 uA[4], uB[4], uC[4];
  auto ldrow = [&](f32x4 (&dst)[4], int i) {
    if (flg) {
      const float* urf = upf + (size_t)(L + i) * 1024 + lane * 4;
#pragma unroll
      for (int c = 0; c < 4; c++) dst[c] = *(const f32x4*)(urf + c * 256);
    } else {
      const unsigned short* ur = up + (size_t)(L + i) * 1024 + lane * 4;
#pragma unroll
      for (int c = 0; c < 4; c++) {
        union { unsigned long long q; unsigned short u[4]; } ld;
        ld.q = *(const unsigned long long*)(ur + c * 256);
        f32x4 v;
#pragma unroll
        for (int j = 0; j < 4; j++) v[j] = bf2f(ld.u[j]);
        dst[c] = v;
      }
    }
  };
  auto dorow = [&](const f32x4 (&uv)[4], int i) {
    f16x4 sh[4];
#pragma unroll
    for (int c = 0; c < 4; c++)
      sh[c] = *(const f16x4*)(St + sidx(i, c * 256 + lane * 4));
    float num1[4][4];
    float s1 = 0.f;
#pragma unroll
    for (int c = 0; c < 4; c++)
#pragma unroll
      for (int j = 0; j < 4; j++) {
        const float s = (float)sh[c][j];
        const float nl = neglog(uv[c][j] + 1e-10f) + 1e-10f;
        num1[c][j] = __expf(s) * __builtin_amdgcn_rcpf(nl);
        s1 += num1[c][j];
      }
    s1 = wsum(s1);
    const float is1 = __builtin_amdgcn_rcpf(s1);
    float num2[4][4];
    float s2 = 0.f;
#pragma unroll
    for (int c = 0; c < 4; c++)
#pragma unroll
      for (int j = 0; j < 4; j++) {
        num2[c][j] = __expf((float)sh[c][j] + num1[c][j] * is1);  // TAU_1 = 1
        s2 += num2[c][j];
      }
    s2 = wsum(s2);
    const float is2 = __builtin_amdgcn_rcpf(s2);
#pragma unroll
    for (int c = 0; c < 4; c++) {
      f16x4 pw;
#pragma unroll
      for (int j = 0; j < 4; j++) pw[j] = (_Float16)(num2[c][j] * is2);
      *(f16x4*)(St + sidx(i, c * 256 + lane * 4)) = pw;
    }
  };

  // issue 3 rows of loads right before the barrier (R1 placement, +1 depth):
  // the barrier's vmcnt drain overlaps with other waves finishing Phase A.
  ldrow(uA, i0);
  ldrow(uB, i0 + 1);
  ldrow(uC, i0 + 2);
  __syncthreads();
  dorow(uA, i0);
  ldrow(uA, i0 + 3);
  dorow(uB, i0 + 1);
  dorow(uC, i0 + 2);
  dorow(uA, i0 + 3);

  // pre-issue first V pair before the barrier (independent of LDS state);
  // latency overlaps with other waves arriving at the barrier.
  const _Float16* vrow = vp + (wave * 16 + lm) * 1024;  // V^T row d
  f16x8 vn0 = *(const f16x8*)(vrow + lq * 8);
  f16x8 vn1 = *(const f16x8*)(vrow + 32 + lq * 8);
  __syncthreads();

  // ---- Phase C: ctx[i][d] = sum_r P[i][r] * V[r][d]  (NT vs V^T) ----
  f32x4 co0 = {0.f, 0.f, 0.f, 0.f}, co1 = {0.f, 0.f, 0.f, 0.f};
#pragma unroll 4
  for (int r0 = 0; r0 < 1024; r0 += 64) {
    const f16x8 va0 = vn0, va1 = vn1;
    if (r0 < 960) {
      vn0 = *(const f16x8*)(vrow + r0 + 64 + lq * 8);
      vn1 = *(const f16x8*)(vrow + r0 + 96 + lq * 8);
    }
    const f16x8 pa0 = *(const f16x8*)(St + sidx(lm, r0 + lq * 8));
    const f16x8 pa1 = *(const f16x8*)(St + sidx(lm, r0 + 32 + lq * 8));
    co0 = __builtin_amdgcn_mfma_f32_16x16x32_f16(pa0, va0, co0, 0, 0, 0);
    co1 = __builtin_amdgcn_mfma_f32_16x16x32_f16(pa1, va1, co1, 0, 0, 0);
  }
  const f32x4 co = co0 + co1;
#pragma unroll
  for (int rg = 0; rg < 4; rg++) {
    const int i = lq * 4 + rg;
    out[(size_t)(b * 1024 + L + i) * 1024 + h * 64 + wave * 16 + lm] = co[rg];
  }
}

extern "C" void kernel_launch(void* const* d_in, const int* in_sizes, int n_in,
                              void* d_out, int out_size, void* d_ws, size_t ws_size,
                              hipStream_t stream) {
  const unsigned short* hidden = (const unsigned short*)d_in[0];
  const unsigned short* mask   = (const unsigned short*)d_in[1];
  const unsigned short* gum    = (const unsigned short*)d_in[2];
  const unsigned short* Wq     = (const unsigned short*)d_in[3];
  const unsigned short* bq     = (const unsigned short*)d_in[4];
  const unsigned short* Wk     = (const unsigned short*)d_in[5];
  const unsigned short* bk     = (const unsigned short*)d_in[6];
  const unsigned short* Wv     = (const unsigned short*)d_in[7];
  const unsigned short* bv     = (const unsigned short*)d_in[8];
  const unsigned short* de     = (const unsigned short*)d_in[9];

  _Float16* cvt16 = (_Float16*)((char*)d_ws + 256);              // 10 MB (dead after qkv)
  _Float16* q_ws  = cvt16 + (size_t)5 * 1024 * 1024;             // 4 MB
  _Float16* k_ws  = q_ws + (size_t)2 * 1024 * 1024;              // 4 MB
  _Float16* v_ws  = k_ws + (size_t)2 * 1024 * 1024;              // 4 MB
  _Float16* vT_ws = cvt16;             // reuse cvt16[0..2M) after qkv consumed it
  _Float16* e16   = cvt16 + (size_t)2 * 1024 * 1024;  // dead Wq slot, 256 KB
  float* out = (float*)d_out;

  cvt_inputs<<<dim3(2048, 4), 256, 0, stream>>>(hidden, Wq, Wk, Wv, gum, cvt16);
  qkv_gemm<<<dim3(32, 24), 256, 0, stream>>>(cvt16, bq, bk, bv, gum,
                                             q_ws, k_ws, v_ws);
  transpose_v_emb<<<dim3(16, 33), 256, 0, stream>>>(v_ws, vT_ws, de, gum, e16);
  attn_kernel<<<2048, 256, 0, stream>>>(q_ws, k_ws, vT_ws, e16, gum, mask, out);
}